// Round 4
// baseline (73.067 us; speedup 1.0000x reference)
//
#include <hip/hip_runtime.h>
#include <hip/hip_bf16.h>

#define BLOCK 256
#define WAVES_PER_BLOCK (BLOCK / 64)
#define GRID_P 1024   // projection blocks (4096 waves)
#define GRID_E 1024   // edge blocks

// Phase 1: per-node projections, split by role:
//   projS[n] = (z_n . W[0:128,0],   z_n . W[0:128,1])     (node used as src)
//   projD[n] = (z_n . W[128:256,0], z_n . W[128:256,1])   (node used as dst)
// Half-wave scheme: lanes 0..31 handle node 2p, lanes 32..63 node 2p+1.
// Lane reads float4 #sub of its row -> the wave reads 1024B fully contiguous.
// Butterfly over 5 stages stays within each 32-lane half (xor masks < 32).
__global__ void __launch_bounds__(BLOCK) proj_kernel(
    const float* __restrict__ Z,
    const float* __restrict__ W,
    float2*      __restrict__ projS,
    float2*      __restrict__ projD,
    int n_nodes)
{
    const int lane = threadIdx.x & 63;
    const int wid  = threadIdx.x >> 6;
    const int sub  = lane & 31;   // float4 index within the 128-float row
    const int half = lane >> 5;   // which node of the pair
    const int gw   = blockIdx.x * WAVES_PER_BLOCK + wid;
    const int nwaves = gridDim.x * WAVES_PER_BLOCK;

    // This lane covers feature rows k0..k0+3.
    const int k0 = 4 * sub;
    float ws[4][2], wd[4][2];
#pragma unroll
    for (int j = 0; j < 4; ++j) {
        ws[j][0] = W[(k0 + j) * 2 + 0];
        ws[j][1] = W[(k0 + j) * 2 + 1];
        wd[j][0] = W[(128 + k0 + j) * 2 + 0];
        wd[j][1] = W[(128 + k0 + j) * 2 + 1];
    }

    const int n_pairs = (n_nodes + 1) >> 1;
    for (int p = gw; p < n_pairs; p += nwaves) {
        const int n = 2 * p + half;
        if (n < n_nodes) {
            const float4 v = ((const float4*)(Z + (size_t)n * 128))[sub];

            float t0 = v.x * ws[0][0] + v.y * ws[1][0] + v.z * ws[2][0] + v.w * ws[3][0];
            float t1 = v.x * ws[0][1] + v.y * ws[1][1] + v.z * ws[2][1] + v.w * ws[3][1];
            float t2 = v.x * wd[0][0] + v.y * wd[1][0] + v.z * wd[2][0] + v.w * wd[3][0];
            float t3 = v.x * wd[0][1] + v.y * wd[1][1] + v.z * wd[2][1] + v.w * wd[3][1];

#pragma unroll
            for (int m = 16; m >= 1; m >>= 1) {   // within-half butterfly
                t0 += __shfl_xor(t0, m, 64);
                t1 += __shfl_xor(t1, m, 64);
                t2 += __shfl_xor(t2, m, 64);
                t3 += __shfl_xor(t3, m, 64);
            }
            if (sub == 0) {
                projS[n] = make_float2(t0, t1);
                projD[n] = make_float2(t2, t3);
            }
        }
    }
}

// Phase 2 (+fused final reduce): per-edge loss from the two 800KB proj tables.
// 2 edges per iteration (int4 edge load, int2 labels). Block partials land in
// d_ws; the last block (agent-scope ticket) does a fixed-order deterministic
// final sum and writes the mean loss.
__global__ void __launch_bounds__(BLOCK) edge_kernel(
    const float2* __restrict__ projS,
    const float2* __restrict__ projD,
    const int*    __restrict__ edges,
    const int*    __restrict__ y,
    float*        __restrict__ partials,
    unsigned int* __restrict__ counter,
    float*        __restrict__ out,
    float inv_m, int n_edges, int nblocks)
{
    const int tid = blockIdx.x * BLOCK + threadIdx.x;
    const int nt  = gridDim.x * BLOCK;

    float acc = 0.0f;
    const int npair = n_edges >> 1;
    for (int i = tid; i < npair; i += nt) {
        const int4 ed = ((const int4*)edges)[i];       // edges 2i, 2i+1
        const int2 yy = ((const int2*)y)[i];

        const float2 a0 = projS[ed.x];
        const float2 b0 = projD[ed.y];
        const float2 a1 = projS[ed.z];
        const float2 b1 = projD[ed.w];

        {
            const float s0 = a0.x + b0.x, s1 = a0.y + b0.y;
            const float mx  = fmaxf(s0, s1);
            const float lse = mx + logf(expf(s0 - mx) + expf(s1 - mx));
            acc += lse - ((yy.x != 0) ? s1 : s0);
        }
        {
            const float s0 = a1.x + b1.x, s1 = a1.y + b1.y;
            const float mx  = fmaxf(s0, s1);
            const float lse = mx + logf(expf(s0 - mx) + expf(s1 - mx));
            acc += lse - ((yy.y != 0) ? s1 : s0);
        }
    }
    // odd-tail (n_edges odd); no-op for 1e6 edges
    for (int e = (npair << 1) + tid; e < n_edges; e += nt) {
        const int2 ed = ((const int2*)edges)[e];
        const float2 a = projS[ed.x];
        const float2 b = projD[ed.y];
        const float s0 = a.x + b.x, s1 = a.y + b.y;
        const float mx  = fmaxf(s0, s1);
        const float lse = mx + logf(expf(s0 - mx) + expf(s1 - mx));
        acc += lse - ((y[e] != 0) ? s1 : s0);
    }

    __shared__ float sm[BLOCK];
    sm[threadIdx.x] = acc;
    __syncthreads();
    for (int off = BLOCK / 2; off >= 1; off >>= 1) {
        if (threadIdx.x < off) sm[threadIdx.x] += sm[threadIdx.x + off];
        __syncthreads();
    }

    __shared__ unsigned int s_ticket;
    if (threadIdx.x == 0) {
        // agent-scope release store of this block's partial, then take a ticket
        __hip_atomic_store(&partials[blockIdx.x], sm[0],
                           __ATOMIC_RELEASE, __HIP_MEMORY_SCOPE_AGENT);
        s_ticket = __hip_atomic_fetch_add(counter, 1u,
                                          __ATOMIC_ACQ_REL, __HIP_MEMORY_SCOPE_AGENT);
    }
    __syncthreads();

    if (s_ticket == (unsigned)(nblocks - 1)) {
        // Last block: deterministic fixed-order reduce of all partials.
        float s = 0.0f;
        for (int i = threadIdx.x; i < nblocks; i += BLOCK)
            s += __hip_atomic_load(&partials[i],
                                   __ATOMIC_RELAXED, __HIP_MEMORY_SCOPE_AGENT);
        sm[threadIdx.x] = s;
        __syncthreads();
        for (int off = BLOCK / 2; off >= 1; off >>= 1) {
            if (threadIdx.x < off) sm[threadIdx.x] += sm[threadIdx.x + off];
            __syncthreads();
        }
        if (threadIdx.x == 0) out[0] = sm[0] * inv_m;
    }
}

extern "C" void kernel_launch(void* const* d_in, const int* in_sizes, int n_in,
                              void* d_out, int out_size, void* d_ws, size_t ws_size,
                              hipStream_t stream)
{
    const float* Z     = (const float*)d_in[0];
    const int*   edges = (const int*)  d_in[1];
    const int*   y     = (const int*)  d_in[2];
    const float* W     = (const float*)d_in[3];
    float* out = (float*)d_out;

    const int n_nodes = in_sizes[0] / 128;
    const int n_edges = in_sizes[1] / 2;

    // Workspace layout: projS | projD | partials | counter
    char* ws = (char*)d_ws;
    float2* projS = (float2*)ws;                     ws += (size_t)n_nodes * sizeof(float2);
    float2* projD = (float2*)ws;                     ws += (size_t)n_nodes * sizeof(float2);
    float*  partials = (float*)ws;                   ws += (size_t)GRID_E * sizeof(float);
    unsigned int* counter = (unsigned int*)ws;

    hipMemsetAsync(counter, 0, sizeof(unsigned int), stream);  // capture-safe

    proj_kernel<<<GRID_P, BLOCK, 0, stream>>>(Z, W, projS, projD, n_nodes);
    edge_kernel<<<GRID_E, BLOCK, 0, stream>>>(projS, projD, edges, y,
                                              partials, counter, out,
                                              1.0f / (float)n_edges, n_edges, GRID_E);
}

// Round 6
// 39.130 us; speedup vs baseline: 1.8673x; 1.8673x over previous
//
#include <hip/hip_runtime.h>
#include <hip/hip_bf16.h>

#define BLOCK 256
#define WAVES_PER_BLOCK (BLOCK / 64)
#define GRID_P 1024   // projection blocks (4096 waves) — proj is at HBM roofline
#define GRID_E 2048   // edge blocks: 524288 threads, 2 edges each, 32 waves/CU

typedef int  vint4 __attribute__((ext_vector_type(4)));
typedef int  vint2 __attribute__((ext_vector_type(2)));

// Phase 1: per-node projections, split by role:
//   projS[n] = (z_n . W[0:128,0],   z_n . W[0:128,1])     (node used as src)
//   projD[n] = (z_n . W[128:256,0], z_n . W[128:256,1])   (node used as dst)
// Half-wave scheme: lanes 0..31 handle node 2p, lanes 32..63 node 2p+1.
// Lane reads float4 #sub of its row -> the wave reads 1024B fully contiguous.
// Butterfly over 5 stages stays within each 32-lane half (xor masks < 32).
__global__ void __launch_bounds__(BLOCK) proj_kernel(
    const float* __restrict__ Z,
    const float* __restrict__ W,
    float2*      __restrict__ projS,
    float2*      __restrict__ projD,
    int n_nodes)
{
    const int lane = threadIdx.x & 63;
    const int wid  = threadIdx.x >> 6;
    const int sub  = lane & 31;   // float4 index within the 128-float row
    const int half = lane >> 5;   // which node of the pair
    const int gw   = blockIdx.x * WAVES_PER_BLOCK + wid;
    const int nwaves = gridDim.x * WAVES_PER_BLOCK;

    // This lane covers feature rows k0..k0+3.
    const int k0 = 4 * sub;
    float ws[4][2], wd[4][2];
#pragma unroll
    for (int j = 0; j < 4; ++j) {
        ws[j][0] = W[(k0 + j) * 2 + 0];
        ws[j][1] = W[(k0 + j) * 2 + 1];
        wd[j][0] = W[(128 + k0 + j) * 2 + 0];
        wd[j][1] = W[(128 + k0 + j) * 2 + 1];
    }

    const int n_pairs = (n_nodes + 1) >> 1;
    for (int p = gw; p < n_pairs; p += nwaves) {
        const int n = 2 * p + half;
        if (n < n_nodes) {
            const float4 v = ((const float4*)(Z + (size_t)n * 128))[sub];

            float t0 = v.x * ws[0][0] + v.y * ws[1][0] + v.z * ws[2][0] + v.w * ws[3][0];
            float t1 = v.x * ws[0][1] + v.y * ws[1][1] + v.z * ws[2][1] + v.w * ws[3][1];
            float t2 = v.x * wd[0][0] + v.y * wd[1][0] + v.z * wd[2][0] + v.w * wd[3][0];
            float t3 = v.x * wd[0][1] + v.y * wd[1][1] + v.z * wd[2][1] + v.w * wd[3][1];

#pragma unroll
            for (int m = 16; m >= 1; m >>= 1) {   // within-half butterfly
                t0 += __shfl_xor(t0, m, 64);
                t1 += __shfl_xor(t1, m, 64);
                t2 += __shfl_xor(t2, m, 64);
                t3 += __shfl_xor(t3, m, 64);
            }
            if (sub == 0) {
                projS[n] = make_float2(t0, t1);
                projD[n] = make_float2(t2, t3);
            }
        }
    }
}

// Phase 2: per-edge loss from the two 800KB proj tables (L2-resident gathers).
// 2 edges per thread (vint4 edge load, vint2 labels) -> 4 independent gathers
// in flight per thread. Edge/label streams use nontemporal loads so the 12MB
// stream does not evict the proj tables from L2. Plain partial stores; the
// deterministic final reduce is a separate tiny kernel (no atomics here).
__global__ void __launch_bounds__(BLOCK) edge_kernel(
    const float2* __restrict__ projS,
    const float2* __restrict__ projD,
    const int*    __restrict__ edges,
    const int*    __restrict__ y,
    float*        __restrict__ partials,
    int n_edges)
{
    const int tid = blockIdx.x * BLOCK + threadIdx.x;
    const int nt  = gridDim.x * BLOCK;

    float acc = 0.0f;
    const int npair = n_edges >> 1;
    for (int i = tid; i < npair; i += nt) {
        const vint4 ed = __builtin_nontemporal_load(((const vint4*)edges) + i);
        const vint2 yy = __builtin_nontemporal_load(((const vint2*)y) + i);

        const float2 a0 = projS[ed.x];
        const float2 b0 = projD[ed.y];
        const float2 a1 = projS[ed.z];
        const float2 b1 = projD[ed.w];

        {
            const float s0 = a0.x + b0.x, s1 = a0.y + b0.y;
            const float mx  = fmaxf(s0, s1);
            const float lse = mx + logf(expf(s0 - mx) + expf(s1 - mx));
            acc += lse - ((yy.x != 0) ? s1 : s0);
        }
        {
            const float s0 = a1.x + b1.x, s1 = a1.y + b1.y;
            const float mx  = fmaxf(s0, s1);
            const float lse = mx + logf(expf(s0 - mx) + expf(s1 - mx));
            acc += lse - ((yy.y != 0) ? s1 : s0);
        }
    }
    // odd-tail (n_edges odd); no-op for 1e6 edges
    for (int e = (npair << 1) + tid; e < n_edges; e += nt) {
        const int2 ed = ((const int2*)edges)[e];
        const float2 a = projS[ed.x];
        const float2 b = projD[ed.y];
        const float s0 = a.x + b.x, s1 = a.y + b.y;
        const float mx  = fmaxf(s0, s1);
        const float lse = mx + logf(expf(s0 - mx) + expf(s1 - mx));
        acc += lse - ((y[e] != 0) ? s1 : s0);
    }

    __shared__ float sm[BLOCK];
    sm[threadIdx.x] = acc;
    __syncthreads();
    for (int off = BLOCK / 2; off >= 1; off >>= 1) {
        if (threadIdx.x < off) sm[threadIdx.x] += sm[threadIdx.x + off];
        __syncthreads();
    }
    if (threadIdx.x == 0) partials[blockIdx.x] = sm[0];
}

// Phase 3: deterministic fixed-order final reduction.
__global__ void __launch_bounds__(BLOCK) reduce_kernel(
    const float* __restrict__ partials, int n,
    float* __restrict__ out, float inv_m)
{
    __shared__ float sm[BLOCK];
    float s = 0.0f;
    for (int i = threadIdx.x; i < n; i += BLOCK) s += partials[i];
    sm[threadIdx.x] = s;
    __syncthreads();
    for (int off = BLOCK / 2; off >= 1; off >>= 1) {
        if (threadIdx.x < off) sm[threadIdx.x] += sm[threadIdx.x + off];
        __syncthreads();
    }
    if (threadIdx.x == 0) out[0] = sm[0] * inv_m;
}

extern "C" void kernel_launch(void* const* d_in, const int* in_sizes, int n_in,
                              void* d_out, int out_size, void* d_ws, size_t ws_size,
                              hipStream_t stream)
{
    const float* Z     = (const float*)d_in[0];
    const int*   edges = (const int*)  d_in[1];
    const int*   y     = (const int*)  d_in[2];
    const float* W     = (const float*)d_in[3];
    float* out = (float*)d_out;

    const int n_nodes = in_sizes[0] / 128;
    const int n_edges = in_sizes[1] / 2;

    // Workspace layout: projS | projD | partials
    char* ws = (char*)d_ws;
    float2* projS = (float2*)ws;   ws += (size_t)n_nodes * sizeof(float2);
    float2* projD = (float2*)ws;   ws += (size_t)n_nodes * sizeof(float2);
    float*  partials = (float*)ws;

    proj_kernel<<<GRID_P, BLOCK, 0, stream>>>(Z, W, projS, projD, n_nodes);
    edge_kernel<<<GRID_E, BLOCK, 0, stream>>>(projS, projD, edges, y,
                                              partials, n_edges);
    reduce_kernel<<<1, BLOCK, 0, stream>>>(partials, GRID_E, out,
                                           1.0f / (float)n_edges);
}

// Round 7
// 32.579 us; speedup vs baseline: 2.2428x; 1.2011x over previous
//
#include <hip/hip_runtime.h>
#include <hip/hip_bf16.h>

#define BLOCK 256
#define WAVES_PER_BLOCK (BLOCK / 64)
#define GRID_P 1024   // projection blocks (4096 waves) — proj is at HBM roofline

typedef int vint4 __attribute__((ext_vector_type(4)));

// Phase 1: per-node logit-difference projections.
//   dS[n] = z_n . (W[0:128,1]   - W[0:128,0])     (node as src)
//   dD[n] = z_n . (W[128:256,1] - W[128:256,0])   (node as dst)
// (2-class identity: loss = softplus(s_wrong - s_correct), and
//  s1 - s0 = dS[src] + dD[dst].)
// Half-wave scheme: lanes 0..31 handle node 2p, lanes 32..63 node 2p+1.
// Lane reads float4 #sub of its row -> the wave reads 1024B fully contiguous.
// Butterfly (5 stages, 2 values) stays within each 32-lane half.
__global__ void __launch_bounds__(BLOCK) proj_kernel(
    const float* __restrict__ Z,
    const float* __restrict__ W,
    float*       __restrict__ dS,
    float*       __restrict__ dD,
    int n_nodes)
{
    const int lane = threadIdx.x & 63;
    const int wid  = threadIdx.x >> 6;
    const int sub  = lane & 31;   // float4 index within the 128-float row
    const int half = lane >> 5;   // which node of the pair
    const int gw   = blockIdx.x * WAVES_PER_BLOCK + wid;
    const int nwaves = gridDim.x * WAVES_PER_BLOCK;

    // This lane covers feature rows k0..k0+3; keep only the class-1 - class-0
    // weight differences.
    const int k0 = 4 * sub;
    float wds[4], wdd[4];
#pragma unroll
    for (int j = 0; j < 4; ++j) {
        wds[j] = W[(k0 + j) * 2 + 1]       - W[(k0 + j) * 2 + 0];
        wdd[j] = W[(128 + k0 + j) * 2 + 1] - W[(128 + k0 + j) * 2 + 0];
    }

    const int n_pairs = (n_nodes + 1) >> 1;
    for (int p = gw; p < n_pairs; p += nwaves) {
        const int n = 2 * p + half;
        if (n < n_nodes) {
            const float4 v = ((const float4*)(Z + (size_t)n * 128))[sub];

            float t0 = v.x * wds[0] + v.y * wds[1] + v.z * wds[2] + v.w * wds[3];
            float t1 = v.x * wdd[0] + v.y * wdd[1] + v.z * wdd[2] + v.w * wdd[3];

#pragma unroll
            for (int m = 16; m >= 1; m >>= 1) {   // within-half butterfly
                t0 += __shfl_xor(t0, m, 64);
                t1 += __shfl_xor(t1, m, 64);
            }
            if (sub == 0) {
                dS[n] = t0;
                dD[n] = t1;
            }
        }
    }
}

__device__ __forceinline__ float softplus(float x) {
    return fmaxf(x, 0.0f) + log1pf(expf(-fabsf(x)));
}

// Phase 2: per-edge loss. 4 edges per thread: 2x vint4 edge loads + 1x vint4
// labels (nontemporal streams), 8 independent 4B gathers from the two 400KB
// L2-resident difference tables, 4 softplus. One pass, no grid-stride.
__global__ void __launch_bounds__(BLOCK) edge_kernel(
    const float* __restrict__ dS,
    const float* __restrict__ dD,
    const int*   __restrict__ edges,
    const int*   __restrict__ y,
    float*       __restrict__ partials,
    int n_edges)
{
    const int tid  = blockIdx.x * BLOCK + threadIdx.x;
    const int base = tid * 4;

    float acc = 0.0f;
    if (base + 3 < n_edges) {
        const vint4 e01 = __builtin_nontemporal_load(((const vint4*)edges) + 2 * tid);
        const vint4 e23 = __builtin_nontemporal_load(((const vint4*)edges) + 2 * tid + 1);
        const vint4 yy  = __builtin_nontemporal_load(((const vint4*)y) + tid);

        float d0 = dS[e01.x] + dD[e01.y];
        float d1 = dS[e01.z] + dD[e01.w];
        float d2 = dS[e23.x] + dD[e23.y];
        float d3 = dS[e23.z] + dD[e23.w];

        d0 = (yy.x != 0) ? -d0 : d0;
        d1 = (yy.y != 0) ? -d1 : d1;
        d2 = (yy.z != 0) ? -d2 : d2;
        d3 = (yy.w != 0) ? -d3 : d3;

        acc = (softplus(d0) + softplus(d1)) + (softplus(d2) + softplus(d3));
    } else if (base < n_edges) {
        for (int e = base; e < n_edges; ++e) {
            float d = dS[edges[2 * e]] + dD[edges[2 * e + 1]];
            d = (y[e] != 0) ? -d : d;
            acc += softplus(d);
        }
    }

    __shared__ float sm[BLOCK];
    sm[threadIdx.x] = acc;
    __syncthreads();
    for (int off = BLOCK / 2; off >= 1; off >>= 1) {
        if (threadIdx.x < off) sm[threadIdx.x] += sm[threadIdx.x + off];
        __syncthreads();
    }
    if (threadIdx.x == 0) partials[blockIdx.x] = sm[0];
}

// Phase 3: deterministic fixed-order final reduction.
__global__ void __launch_bounds__(BLOCK) reduce_kernel(
    const float* __restrict__ partials, int n,
    float* __restrict__ out, float inv_m)
{
    __shared__ float sm[BLOCK];
    float s = 0.0f;
    for (int i = threadIdx.x; i < n; i += BLOCK) s += partials[i];
    sm[threadIdx.x] = s;
    __syncthreads();
    for (int off = BLOCK / 2; off >= 1; off >>= 1) {
        if (threadIdx.x < off) sm[threadIdx.x] += sm[threadIdx.x + off];
        __syncthreads();
    }
    if (threadIdx.x == 0) out[0] = sm[0] * inv_m;
}

extern "C" void kernel_launch(void* const* d_in, const int* in_sizes, int n_in,
                              void* d_out, int out_size, void* d_ws, size_t ws_size,
                              hipStream_t stream)
{
    const float* Z     = (const float*)d_in[0];
    const int*   edges = (const int*)  d_in[1];
    const int*   y     = (const int*)  d_in[2];
    const float* W     = (const float*)d_in[3];
    float* out = (float*)d_out;

    const int n_nodes = in_sizes[0] / 128;
    const int n_edges = in_sizes[1] / 2;

    const int grid_e = (n_edges + 4 * BLOCK - 1) / (4 * BLOCK);

    // Workspace layout: dS | dD | partials
    char* ws = (char*)d_ws;
    float* dS = (float*)ws;        ws += (size_t)n_nodes * sizeof(float);
    float* dD = (float*)ws;        ws += (size_t)n_nodes * sizeof(float);
    float* partials = (float*)ws;

    proj_kernel<<<GRID_P, BLOCK, 0, stream>>>(Z, W, dS, dD, n_nodes);
    edge_kernel<<<grid_e, BLOCK, 0, stream>>>(dS, dD, edges, y, partials, n_edges);
    reduce_kernel<<<1, BLOCK, 0, stream>>>(partials, grid_e, out,
                                           1.0f / (float)n_edges);
}